// Round 5
// baseline (1181.749 us; speedup 1.0000x reference)
//
#include <hip/hip_runtime.h>
#include <hip/hip_bf16.h>

// LSTM classifier: B=64, S=2048, E=H=128, OUT=1.
// Phase A (parallel): pre[t][g][b][j] = bias[g][j] + emb[x[b,t]] . W_g[j][0:128]
// Phase B (sequential, 1 WG per batch, 8 waves): per-step h-matmul via
//   mfma_f32_16x16x32_bf16, M=1. Weights = resident B-fragments (bf16 hi/lo).
//   KEY FIX vs round 4: in-loop __syncthreads() drained vmcnt(0) every step,
//   exposing ~900-cyc HBM latency of the pre-stream prefetch. Replaced with
//   raw s_barrier + lgkmcnt(0)-only wait (HK counted-vmcnt discipline):
//   prefetch loads now stay in flight across barriers. Prefetch deepened to 4.

#define LSTM_B 64
#define LSTM_E 128
#define LSTM_H 128
#define ROWW   256           // E+H, weight row width
#define TSTRIDE (2*LSTM_B*LSTM_H)   // floats per timestep in pre buffer

typedef __attribute__((ext_vector_type(8))) short bf16x8;
typedef __attribute__((ext_vector_type(4))) float f32x4;

__device__ __forceinline__ float fast_rcp(float x) {
    return __builtin_amdgcn_rcpf(x);
}
__device__ __forceinline__ float sigmoidf_(float x) {
    return fast_rcp(1.0f + __expf(-x));
}
__device__ __forceinline__ float tanh_fast(float x) {
    float ax = fabsf(x);
    float t = __expf(-2.0f * ax);          // in (0,1], no overflow
    float r = (1.0f - t) * fast_rcp(1.0f + t);
    return copysignf(r, x);
}
__device__ __forceinline__ short f2bf(float f) {   // round-to-nearest-even
    union { float f; unsigned u; } v; v.f = f;
    unsigned r = (v.u + 0x7FFFu + ((v.u >> 16) & 1u)) >> 16;
    return (short)r;
}
__device__ __forceinline__ float bf2f(short s) {
    union { unsigned u; float f; } v; v.u = ((unsigned)(unsigned short)s) << 16;
    return v.f;
}

// Producer-side LDS flush + raw barrier: does NOT drain vmcnt, so global
// prefetch loads survive the barrier (unlike __syncthreads).
__device__ __forceinline__ void lds_barrier() {
    asm volatile("s_waitcnt lgkmcnt(0)" ::: "memory");
    __builtin_amdgcn_s_barrier();
    asm volatile("" ::: "memory");
}

// ---------------- Phase A: input projections for both gates ----------------
__global__ __launch_bounds__(256) void lstm_phaseA(
    const int* __restrict__ x, const float* __restrict__ emb,
    const float* __restrict__ Wf, const float* __restrict__ bf,
    const float* __restrict__ Wc, const float* __restrict__ bc,
    float* __restrict__ pre, int t0, int S)
{
    __shared__ __align__(16) float emb_s[16][LSTM_E];
    __shared__ int idx_s[16];

    const int tile = blockIdx.x;
    const int t  = t0 + (tile >> 2);
    const int b0 = (tile & 3) << 4;
    const int tid = threadIdx.x;

    if (tid < 16) idx_s[tid] = x[(size_t)(b0 + tid) * S + t];
    __syncthreads();
    {
        const int r  = tid >> 4;
        const int cp = (tid & 15) << 3;
        const float* src = emb + (size_t)idx_s[r] * LSTM_E + cp;
        float4 v0 = *(const float4*)src;
        float4 v1 = *(const float4*)(src + 4);
        *(float4*)&emb_s[r][cp]     = v0;
        *(float4*)&emb_s[r][cp + 4] = v1;
    }
    __syncthreads();

    const int g = tid >> 7, j = tid & 127;
    const float* Wrow = (g ? Wc : Wf) + (size_t)j * ROWW;
    const float bias  = (g ? bc : bf)[j];

    float acc[16];
#pragma unroll
    for (int b = 0; b < 16; ++b) acc[b] = bias;

    for (int kc = 0; kc < LSTM_E; kc += 16) {
        float4 wv[4];
#pragma unroll
        for (int i = 0; i < 4; ++i) wv[i] = *(const float4*)(Wrow + kc + 4*i);
#pragma unroll
        for (int b = 0; b < 16; ++b) {
#pragma unroll
            for (int i = 0; i < 4; ++i) {
                float4 ev = *(const float4*)&emb_s[b][kc + 4*i];
                acc[b] += ev.x*wv[i].x + ev.y*wv[i].y + ev.z*wv[i].z + ev.w*wv[i].w;
            }
        }
    }

    float* dst = pre + ((size_t)(t - t0) * 2 + g) * (LSTM_B * LSTM_H)
                     + (size_t)b0 * LSTM_H + j;
#pragma unroll
    for (int b = 0; b < 16; ++b) dst[(size_t)b * LSTM_H] = acc[b];
}

// ---------------- Phase B: the recurrence (MFMA) ----------------
// 64 blocks (1 batch each), 512 threads = 8 waves.
// Wave w, lane l: output j = 16*w + (l&15).
// B-frag (W, K=32 x N=16): lane l -> col n=l&15, k = 32*ks + 8*(l>>4) + e.
// A-frag (h, M=16 x K=32): all 16-lane groups read the same row-0 bytes ->
//   4-address wave broadcast, conflict-free (round-4: SQ_LDS_BANK_CONFLICT=0).
__global__ __launch_bounds__(512, 2) void lstm_phaseB(
    const float* __restrict__ Wf, const float* __restrict__ Wc,
    const float* __restrict__ Wfc, const float* __restrict__ bfc,
    const float* __restrict__ pre, float* __restrict__ state,
    float* __restrict__ out, int t0, int t1, int S)
{
    __shared__ __align__(16) short h_s[2][LSTM_H];   // bf16 h, double-buffered
    __shared__ float red_s[LSTM_H];

    const int b    = blockIdx.x;
    const int tid  = threadIdx.x;
    const int lane = tid & 63;
    const int w    = tid >> 6;          // wave 0..7
    const int jj   = 16 * w + (lane & 15);
    const int kb   = ((lane >> 4) & 3) * 8;   // k-sub-base within a kstep

    // ---- resident B-fragments: W h-part, bf16 hi/lo split ----
    bf16x8 bhiF[4], bloF[4], bhiC[4], bloC[4];
#pragma unroll
    for (int ks = 0; ks < 4; ++ks) {
        const float* rF = Wf + (size_t)jj * ROWW + LSTM_E + 32*ks + kb;
        const float* rC = Wc + (size_t)jj * ROWW + LSTM_E + 32*ks + kb;
        float4 f0 = *(const float4*)rF, f1 = *(const float4*)(rF + 4);
        float4 c0 = *(const float4*)rC, c1 = *(const float4*)(rC + 4);
        float ef[8] = {f0.x,f0.y,f0.z,f0.w,f1.x,f1.y,f1.z,f1.w};
        float ec[8] = {c0.x,c0.y,c0.z,c0.w,c1.x,c1.y,c1.z,c1.w};
#pragma unroll
        for (int e = 0; e < 8; ++e) {
            short h1 = f2bf(ef[e]);  bhiF[ks][e] = h1;  bloF[ks][e] = f2bf(ef[e] - bf2f(h1));
            short h2 = f2bf(ec[e]);  bhiC[ks][e] = h2;  bloC[ks][e] = f2bf(ec[e] - bf2f(h2));
        }
    }

    float c = 0.0f, h_last = 0.0f;
    if (t0 == 0) {
        if (tid < LSTM_H) h_s[0][tid] = 0;
    } else {
        if (tid < LSTM_H) h_s[0][tid] = f2bf(state[(size_t)b * LSTM_H + tid]);
        c = state[LSTM_B * LSTM_H + (size_t)b * LSTM_H + jj];
    }

    // pre stream, 4-deep prefetch (scalar rotation -> static indexing)
    const float* prepF = pre + (size_t)b * LSTM_H + jj;        // [t][g=0][b][j]
    const float* prepC = prepF + LSTM_B * LSTM_H;              // g=1
    const int NT = t1 - t0;
    float pf0 = prepF[0], pc0 = prepC[0];
    float pf1 = (NT > 1) ? prepF[1*TSTRIDE] : 0.f, pc1 = (NT > 1) ? prepC[1*TSTRIDE] : 0.f;
    float pf2 = (NT > 2) ? prepF[2*TSTRIDE] : 0.f, pc2 = (NT > 2) ? prepC[2*TSTRIDE] : 0.f;
    float pf3 = (NT > 3) ? prepF[3*TSTRIDE] : 0.f, pc3 = (NT > 3) ? prepC[3*TSTRIDE] : 0.f;
    __syncthreads();   // once, pre-loop: full drain here is harmless

    const f32x4 zz = {0.f, 0.f, 0.f, 0.f};
    int cur = 0;
    for (int t = t0; t < t1; ++t) {
        // A-fragments: 4 broadcast ds_read_b128 from the 256B h row
        const short* hb = &h_s[cur][0];
        bf16x8 a0 = *(const bf16x8*)(hb + 0*32 + kb);
        bf16x8 a1 = *(const bf16x8*)(hb + 1*32 + kb);
        bf16x8 a2 = *(const bf16x8*)(hb + 2*32 + kb);
        bf16x8 a3 = *(const bf16x8*)(hb + 3*32 + kb);

        float af = pf0, ac = pc0;
        pf0 = pf1; pf1 = pf2; pf2 = pf3;
        pc0 = pc1; pc1 = pc2; pc2 = pc3;
        {   // refill slot 3 (consumed 4 steps from now; never waited at barrier)
            const int tp = t - t0 + 4;
            if (tp < NT) { pf3 = prepF[(size_t)tp * TSTRIDE];
                           pc3 = prepC[(size_t)tp * TSTRIDE]; }
        }

        // gate f: 4 independent depth-2 chains (hi then lo)
        f32x4 f0 = __builtin_amdgcn_mfma_f32_16x16x32_bf16(a0, bhiF[0], zz, 0, 0, 0);
        f32x4 f1 = __builtin_amdgcn_mfma_f32_16x16x32_bf16(a1, bhiF[1], zz, 0, 0, 0);
        f32x4 f2 = __builtin_amdgcn_mfma_f32_16x16x32_bf16(a2, bhiF[2], zz, 0, 0, 0);
        f32x4 f3 = __builtin_amdgcn_mfma_f32_16x16x32_bf16(a3, bhiF[3], zz, 0, 0, 0);
        f0 = __builtin_amdgcn_mfma_f32_16x16x32_bf16(a0, bloF[0], f0, 0, 0, 0);
        f1 = __builtin_amdgcn_mfma_f32_16x16x32_bf16(a1, bloF[1], f1, 0, 0, 0);
        f2 = __builtin_amdgcn_mfma_f32_16x16x32_bf16(a2, bloF[2], f2, 0, 0, 0);
        f3 = __builtin_amdgcn_mfma_f32_16x16x32_bf16(a3, bloF[3], f3, 0, 0, 0);
        // gate c
        f32x4 g0 = __builtin_amdgcn_mfma_f32_16x16x32_bf16(a0, bhiC[0], zz, 0, 0, 0);
        f32x4 g1 = __builtin_amdgcn_mfma_f32_16x16x32_bf16(a1, bhiC[1], zz, 0, 0, 0);
        f32x4 g2 = __builtin_amdgcn_mfma_f32_16x16x32_bf16(a2, bhiC[2], zz, 0, 0, 0);
        f32x4 g3 = __builtin_amdgcn_mfma_f32_16x16x32_bf16(a3, bhiC[3], zz, 0, 0, 0);
        g0 = __builtin_amdgcn_mfma_f32_16x16x32_bf16(a0, bloC[0], g0, 0, 0, 0);
        g1 = __builtin_amdgcn_mfma_f32_16x16x32_bf16(a1, bloC[1], g1, 0, 0, 0);
        g2 = __builtin_amdgcn_mfma_f32_16x16x32_bf16(a2, bloC[2], g2, 0, 0, 0);
        g3 = __builtin_amdgcn_mfma_f32_16x16x32_bf16(a3, bloC[3], g3, 0, 0, 0);

        af += (f0[0] + f1[0]) + (f2[0] + f3[0]);   // C row 0 = the real batch
        ac += (g0[0] + g1[0]) + (g2[0] + g3[0]);

        float gg = sigmoidf_(af);        // shared gate (source bug: f==i==o)
        float ct = tanh_fast(ac);
        c = gg * (c + ct);
        float hn = gg * tanh_fast(c);
        h_last = hn;
        if (lane < 16) h_s[cur ^ 1][jj] = f2bf(hn);
        lds_barrier();                   // lgkmcnt(0)+s_barrier, vmcnt NOT drained
        cur ^= 1;
    }

    if (t1 == S) {
        if (lane < 16) red_s[jj] = h_last * Wfc[jj];
        __syncthreads();
        if (tid < 64) {
            float s = red_s[tid] + red_s[tid + 64];
            s += __shfl_down(s, 32, 64);
            s += __shfl_down(s, 16, 64);
            s += __shfl_down(s, 8, 64);
            s += __shfl_down(s, 4, 64);
            s += __shfl_down(s, 2, 64);
            s += __shfl_down(s, 1, 64);
            if (tid == 0) out[b] = sigmoidf_(s + bfc[0]);
        }
    } else {
        if (lane < 16) {
            state[(size_t)b * LSTM_H + jj] = h_last;
            state[LSTM_B * LSTM_H + (size_t)b * LSTM_H + jj] = c;
        }
    }
}

extern "C" void kernel_launch(void* const* d_in, const int* in_sizes, int n_in,
                              void* d_out, int out_size, void* d_ws, size_t ws_size,
                              hipStream_t stream) {
    const int*   x   = (const int*)d_in[0];
    const float* emb = (const float*)d_in[1];
    const float* Wf  = (const float*)d_in[2];
    const float* bf  = (const float*)d_in[3];
    const float* Wc  = (const float*)d_in[4];
    const float* bc  = (const float*)d_in[5];
    const float* Wfc = (const float*)d_in[6];
    const float* bfc = (const float*)d_in[7];
    float* out = (float*)d_out;

    const int S = in_sizes[0] / LSTM_B;           // 2048

    float* state = (float*)d_ws;                              // h[64][128], c[64][128]
    float* pre   = state + (size_t)2 * LSTM_B * LSTM_H;       // + 64KB

    const size_t state_bytes = (size_t)2 * LSTM_B * LSTM_H * sizeof(float);
    const size_t per_t_bytes = (size_t)TSTRIDE * sizeof(float);   // 64 KB per step
    size_t avail = (ws_size > state_bytes) ? (ws_size - state_bytes) : 0;
    int CH = (int)(avail / per_t_bytes);
    if (CH > S) CH = S;
    if (CH < 1) CH = 1;   // requires ws_size >= 128KB + state

    for (int t0 = 0; t0 < S; t0 += CH) {
        const int t1 = (t0 + CH < S) ? (t0 + CH) : S;
        lstm_phaseA<<<(t1 - t0) * 4, 256, 0, stream>>>(x, emb, Wf, bf, Wc, bc,
                                                       pre, t0, S);
        lstm_phaseB<<<LSTM_B, 512, 0, stream>>>(Wf, Wc, Wfc, bfc, pre, state,
                                                out, t0, t1, S);
    }
}

// Round 6
// 881.494 us; speedup vs baseline: 1.3406x; 1.3406x over previous
//
#include <hip/hip_runtime.h>
#include <hip/hip_bf16.h>

// LSTM classifier: B=64, S=2048, E=H=128, OUT=1.
// Phase A (parallel): pre[t][g][b][j] = bias[g][j] + emb[x[b,t]] . W_g[j][0:128]
// Phase B (sequential, 1 WG per batch, 8 waves): per-step h-matmul via
//   mfma_f32_16x16x32_bf16, M=1. Weights = resident bf16 B-fragments.
// Round-6 change (single variable vs round-4's 930us): weights are bf16 HI
//   only (no hi/lo split) -> 8 MFMA/wave/step instead of 16. Rationale: one
//   16x16x32 MFMA costs ~16-19 SIMD-cycles (2075 TF/256CU = 844 FLOP/cyc/SIMD),
//   so round-4 spent ~510 cyc/step/SIMD in the matrix pipe (~47% of the step;
//   reported MfmaUtil 11.7 is the gfx94x formula under-counting by 4x).
//   Accuracy: bf16 weight rounding ~4.5e-4 per gate sum, same order as the
//   h bf16 quantization already in place (which measures absmax 0.0).

#define LSTM_B 64
#define LSTM_E 128
#define LSTM_H 128
#define ROWW   256           // E+H, weight row width
#define TSTRIDE (2*LSTM_B*LSTM_H)   // floats per timestep in pre buffer

typedef __attribute__((ext_vector_type(8))) short bf16x8;
typedef __attribute__((ext_vector_type(4))) float f32x4;

__device__ __forceinline__ float fast_rcp(float x) {
    return __builtin_amdgcn_rcpf(x);
}
__device__ __forceinline__ float sigmoidf_(float x) {
    return fast_rcp(1.0f + __expf(-x));
}
__device__ __forceinline__ float tanh_fast(float x) {
    float ax = fabsf(x);
    float t = __expf(-2.0f * ax);          // in (0,1], no overflow
    float r = (1.0f - t) * fast_rcp(1.0f + t);
    return copysignf(r, x);
}
__device__ __forceinline__ short f2bf(float f) {   // round-to-nearest-even
    union { float f; unsigned u; } v; v.f = f;
    unsigned r = (v.u + 0x7FFFu + ((v.u >> 16) & 1u)) >> 16;
    return (short)r;
}

// ---------------- Phase A: input projections for both gates ----------------
__global__ __launch_bounds__(256) void lstm_phaseA(
    const int* __restrict__ x, const float* __restrict__ emb,
    const float* __restrict__ Wf, const float* __restrict__ bf,
    const float* __restrict__ Wc, const float* __restrict__ bc,
    float* __restrict__ pre, int t0, int S)
{
    __shared__ __align__(16) float emb_s[16][LSTM_E];
    __shared__ int idx_s[16];

    const int tile = blockIdx.x;
    const int t  = t0 + (tile >> 2);
    const int b0 = (tile & 3) << 4;
    const int tid = threadIdx.x;

    if (tid < 16) idx_s[tid] = x[(size_t)(b0 + tid) * S + t];
    __syncthreads();
    {
        const int r  = tid >> 4;
        const int cp = (tid & 15) << 3;
        const float* src = emb + (size_t)idx_s[r] * LSTM_E + cp;
        float4 v0 = *(const float4*)src;
        float4 v1 = *(const float4*)(src + 4);
        *(float4*)&emb_s[r][cp]     = v0;
        *(float4*)&emb_s[r][cp + 4] = v1;
    }
    __syncthreads();

    const int g = tid >> 7, j = tid & 127;
    const float* Wrow = (g ? Wc : Wf) + (size_t)j * ROWW;
    const float bias  = (g ? bc : bf)[j];

    float acc[16];
#pragma unroll
    for (int b = 0; b < 16; ++b) acc[b] = bias;

    for (int kc = 0; kc < LSTM_E; kc += 16) {
        float4 wv[4];
#pragma unroll
        for (int i = 0; i < 4; ++i) wv[i] = *(const float4*)(Wrow + kc + 4*i);
#pragma unroll
        for (int b = 0; b < 16; ++b) {
#pragma unroll
            for (int i = 0; i < 4; ++i) {
                float4 ev = *(const float4*)&emb_s[b][kc + 4*i];
                acc[b] += ev.x*wv[i].x + ev.y*wv[i].y + ev.z*wv[i].z + ev.w*wv[i].w;
            }
        }
    }

    float* dst = pre + ((size_t)(t - t0) * 2 + g) * (LSTM_B * LSTM_H)
                     + (size_t)b0 * LSTM_H + j;
#pragma unroll
    for (int b = 0; b < 16; ++b) dst[(size_t)b * LSTM_H] = acc[b];
}

// ---------------- Phase B: the recurrence (MFMA) ----------------
// 64 blocks (1 batch each), 512 threads = 8 waves.
// Wave w, lane l: output j = 16*w + (l&15).
// B-frag (W, K=32 x N=16): lane l -> col n=l&15, k = 32*ks + 8*(l>>4) + e.
// A-frag (h, M=16 x K=32): all 16-lane groups read the same row-0 bytes ->
//   4-address wave broadcast, conflict-free (round-4: SQ_LDS_BANK_CONFLICT=0).
__global__ __launch_bounds__(512, 2) void lstm_phaseB(
    const float* __restrict__ Wf, const float* __restrict__ Wc,
    const float* __restrict__ Wfc, const float* __restrict__ bfc,
    const float* __restrict__ pre, float* __restrict__ state,
    float* __restrict__ out, int t0, int t1, int S)
{
    __shared__ __align__(16) short h_s[2][LSTM_H];   // bf16 h, double-buffered
    __shared__ float red_s[LSTM_H];

    const int b    = blockIdx.x;
    const int tid  = threadIdx.x;
    const int lane = tid & 63;
    const int w    = tid >> 6;          // wave 0..7
    const int jj   = 16 * w + (lane & 15);
    const int kb   = ((lane >> 4) & 3) * 8;   // k-sub-base within a kstep

    // ---- resident B-fragments: W h-part, bf16 (hi only) ----
    bf16x8 bF[4], bC[4];
#pragma unroll
    for (int ks = 0; ks < 4; ++ks) {
        const float* rF = Wf + (size_t)jj * ROWW + LSTM_E + 32*ks + kb;
        const float* rC = Wc + (size_t)jj * ROWW + LSTM_E + 32*ks + kb;
        float4 f0 = *(const float4*)rF, f1 = *(const float4*)(rF + 4);
        float4 c0 = *(const float4*)rC, c1 = *(const float4*)(rC + 4);
        float ef[8] = {f0.x,f0.y,f0.z,f0.w,f1.x,f1.y,f1.z,f1.w};
        float ec[8] = {c0.x,c0.y,c0.z,c0.w,c1.x,c1.y,c1.z,c1.w};
#pragma unroll
        for (int e = 0; e < 8; ++e) {
            bF[ks][e] = f2bf(ef[e]);
            bC[ks][e] = f2bf(ec[e]);
        }
    }

    float c = 0.0f, h_last = 0.0f;
    if (t0 == 0) {
        if (tid < LSTM_H) h_s[0][tid] = 0;
    } else {
        if (tid < LSTM_H) h_s[0][tid] = f2bf(state[(size_t)b * LSTM_H + tid]);
        c = state[LSTM_B * LSTM_H + (size_t)b * LSTM_H + jj];
    }

    // pre stream, 2-deep prefetch (all lanes; lanes>=16 duplicate, coalesced)
    const float* prepF = pre + (size_t)b * LSTM_H + jj;        // [t][g=0][b][j]
    const float* prepC = prepF + LSTM_B * LSTM_H;              // g=1
    float pf0 = prepF[0], pc0 = prepC[0];
    float pf1 = 0.f, pc1 = 0.f;
    if (t1 - t0 > 1) { pf1 = prepF[TSTRIDE]; pc1 = prepC[TSTRIDE]; }
    __syncthreads();

    const f32x4 zz = {0.f, 0.f, 0.f, 0.f};
    int cur = 0;
    for (int t = t0; t < t1; ++t) {
        // A-fragments: 4 broadcast ds_read_b128 from the 256B h row
        const short* hb = &h_s[cur][0];
        bf16x8 a0 = *(const bf16x8*)(hb + 0*32 + kb);
        bf16x8 a1 = *(const bf16x8*)(hb + 1*32 + kb);
        bf16x8 a2 = *(const bf16x8*)(hb + 2*32 + kb);
        bf16x8 a3 = *(const bf16x8*)(hb + 3*32 + kb);

        float af = pf0, ac = pc0;
        pf0 = pf1; pc0 = pc1;
        if ((t - t0 + 2) < (t1 - t0)) {
            pf1 = prepF[(size_t)(t - t0 + 2) * TSTRIDE];
            pc1 = prepC[(size_t)(t - t0 + 2) * TSTRIDE];
        }

        // 8 independent MFMAs (4 k-slices x 2 gates), depth-1 chains
        f32x4 f0 = __builtin_amdgcn_mfma_f32_16x16x32_bf16(a0, bF[0], zz, 0, 0, 0);
        f32x4 f1 = __builtin_amdgcn_mfma_f32_16x16x32_bf16(a1, bF[1], zz, 0, 0, 0);
        f32x4 f2 = __builtin_amdgcn_mfma_f32_16x16x32_bf16(a2, bF[2], zz, 0, 0, 0);
        f32x4 f3 = __builtin_amdgcn_mfma_f32_16x16x32_bf16(a3, bF[3], zz, 0, 0, 0);
        f32x4 g0 = __builtin_amdgcn_mfma_f32_16x16x32_bf16(a0, bC[0], zz, 0, 0, 0);
        f32x4 g1 = __builtin_amdgcn_mfma_f32_16x16x32_bf16(a1, bC[1], zz, 0, 0, 0);
        f32x4 g2 = __builtin_amdgcn_mfma_f32_16x16x32_bf16(a2, bC[2], zz, 0, 0, 0);
        f32x4 g3 = __builtin_amdgcn_mfma_f32_16x16x32_bf16(a3, bC[3], zz, 0, 0, 0);

        af += (f0[0] + f1[0]) + (f2[0] + f3[0]);   // C row 0 = the real batch
        ac += (g0[0] + g1[0]) + (g2[0] + g3[0]);

        float gg = sigmoidf_(af);        // shared gate (source bug: f==i==o)
        float ct = tanh_fast(ac);
        c = gg * (c + ct);
        float hn = gg * tanh_fast(c);
        h_last = hn;
        if (lane < 16) h_s[cur ^ 1][jj] = f2bf(hn);
        __syncthreads();                 // single barrier per step
        cur ^= 1;
    }

    if (t1 == S) {
        if (lane < 16) red_s[jj] = h_last * Wfc[jj];
        __syncthreads();
        if (tid < 64) {
            float s = red_s[tid] + red_s[tid + 64];
            s += __shfl_down(s, 32, 64);
            s += __shfl_down(s, 16, 64);
            s += __shfl_down(s, 8, 64);
            s += __shfl_down(s, 4, 64);
            s += __shfl_down(s, 2, 64);
            s += __shfl_down(s, 1, 64);
            if (tid == 0) out[b] = sigmoidf_(s + bfc[0]);
        }
    } else {
        if (lane < 16) {
            state[(size_t)b * LSTM_H + jj] = h_last;
            state[LSTM_B * LSTM_H + (size_t)b * LSTM_H + jj] = c;
        }
    }
}

extern "C" void kernel_launch(void* const* d_in, const int* in_sizes, int n_in,
                              void* d_out, int out_size, void* d_ws, size_t ws_size,
                              hipStream_t stream) {
    const int*   x   = (const int*)d_in[0];
    const float* emb = (const float*)d_in[1];
    const float* Wf  = (const float*)d_in[2];
    const float* bf  = (const float*)d_in[3];
    const float* Wc  = (const float*)d_in[4];
    const float* bc  = (const float*)d_in[5];
    const float* Wfc = (const float*)d_in[6];
    const float* bfc = (const float*)d_in[7];
    float* out = (float*)d_out;

    const int S = in_sizes[0] / LSTM_B;           // 2048

    float* state = (float*)d_ws;                              // h[64][128], c[64][128]
    float* pre   = state + (size_t)2 * LSTM_B * LSTM_H;       // + 64KB

    const size_t state_bytes = (size_t)2 * LSTM_B * LSTM_H * sizeof(float);
    const size_t per_t_bytes = (size_t)TSTRIDE * sizeof(float);   // 64 KB per step
    size_t avail = (ws_size > state_bytes) ? (ws_size - state_bytes) : 0;
    int CH = (int)(avail / per_t_bytes);
    if (CH > S) CH = S;
    if (CH < 1) CH = 1;   // requires ws_size >= 128KB + state

    for (int t0 = 0; t0 < S; t0 += CH) {
        const int t1 = (t0 + CH < S) ? (t0 + CH) : S;
        lstm_phaseA<<<(t1 - t0) * 4, 256, 0, stream>>>(x, emb, Wf, bf, Wc, bc,
                                                       pre, t0, S);
        lstm_phaseB<<<LSTM_B, 512, 0, stream>>>(Wf, Wc, Wfc, bfc, pre, state,
                                                out, t0, t1, S);
    }
}

// Round 7
// 834.362 us; speedup vs baseline: 1.4164x; 1.0565x over previous
//
#include <hip/hip_runtime.h>
#include <hip/hip_bf16.h>

// LSTM classifier: B=64, S=2048, E=H=128, OUT=1.
// Phase A (parallel): pre[t][g][b][j] = bias[g][j] + emb[x[b,t]] . W_g[j][0:128]
// Phase B (sequential, 1 WG per batch, 8 waves): per-step h-matmul via
//   mfma_f32_16x16x32_bf16, M=1, bf16 weights resident as B-fragments.
// Round-7 changes (step was ISSUE-bound: active-CU MfmaUtil ~31% + VALUBusy
//   ~56% = 86% of the 837-cyc step):
//   1. MFMAs chained through the C accumulator (2 chains of 4) -> kills the
//      per-step AGPR zero-init/readback moves and the 8 tree-adds.
//   2. t-loop unrolled x2 -> cur-flip and prefetch rotation become renaming.
//   3. f2bf via v_cvt_pk_bf16_f32 (1 op vs 4).

#define LSTM_B 64
#define LSTM_E 128
#define LSTM_H 128
#define ROWW   256           // E+H, weight row width
#define TSTRIDE (2*LSTM_B*LSTM_H)   // floats per timestep in pre buffer

typedef __attribute__((ext_vector_type(8))) short bf16x8;
typedef __attribute__((ext_vector_type(4))) float f32x4;

__device__ __forceinline__ float fast_rcp(float x) {
    return __builtin_amdgcn_rcpf(x);
}
__device__ __forceinline__ float sigmoidf_(float x) {
    return fast_rcp(1.0f + __expf(-x));
}
__device__ __forceinline__ float tanh_fast(float x) {
    float ax = fabsf(x);
    float t = __expf(-2.0f * ax);          // in (0,1], no overflow
    float r = (1.0f - t) * fast_rcp(1.0f + t);
    return copysignf(r, x);
}
__device__ __forceinline__ short f2bf(float f) {   // round-to-nearest-even
    union { float f; unsigned u; } v; v.f = f;
    unsigned r = (v.u + 0x7FFFu + ((v.u >> 16) & 1u)) >> 16;
    return (short)r;
}
__device__ __forceinline__ short f2bf_hw(float f) {  // v_cvt_pk_bf16_f32 (RNE)
    unsigned r;
    float z = 0.0f;
    asm("v_cvt_pk_bf16_f32 %0, %1, %2" : "=v"(r) : "v"(f), "v"(z));
    return (short)(r & 0xFFFFu);
}

// ---------------- Phase A: input projections for both gates ----------------
__global__ __launch_bounds__(256) void lstm_phaseA(
    const int* __restrict__ x, const float* __restrict__ emb,
    const float* __restrict__ Wf, const float* __restrict__ bf,
    const float* __restrict__ Wc, const float* __restrict__ bc,
    float* __restrict__ pre, int t0, int S)
{
    __shared__ __align__(16) float emb_s[16][LSTM_E];
    __shared__ int idx_s[16];

    const int tile = blockIdx.x;
    const int t  = t0 + (tile >> 2);
    const int b0 = (tile & 3) << 4;
    const int tid = threadIdx.x;

    if (tid < 16) idx_s[tid] = x[(size_t)(b0 + tid) * S + t];
    __syncthreads();
    {
        const int r  = tid >> 4;
        const int cp = (tid & 15) << 3;
        const float* src = emb + (size_t)idx_s[r] * LSTM_E + cp;
        float4 v0 = *(const float4*)src;
        float4 v1 = *(const float4*)(src + 4);
        *(float4*)&emb_s[r][cp]     = v0;
        *(float4*)&emb_s[r][cp + 4] = v1;
    }
    __syncthreads();

    const int g = tid >> 7, j = tid & 127;
    const float* Wrow = (g ? Wc : Wf) + (size_t)j * ROWW;
    const float bias  = (g ? bc : bf)[j];

    float acc[16];
#pragma unroll
    for (int b = 0; b < 16; ++b) acc[b] = bias;

    for (int kc = 0; kc < LSTM_E; kc += 16) {
        float4 wv[4];
#pragma unroll
        for (int i = 0; i < 4; ++i) wv[i] = *(const float4*)(Wrow + kc + 4*i);
#pragma unroll
        for (int b = 0; b < 16; ++b) {
#pragma unroll
            for (int i = 0; i < 4; ++i) {
                float4 ev = *(const float4*)&emb_s[b][kc + 4*i];
                acc[b] += ev.x*wv[i].x + ev.y*wv[i].y + ev.z*wv[i].z + ev.w*wv[i].w;
            }
        }
    }

    float* dst = pre + ((size_t)(t - t0) * 2 + g) * (LSTM_B * LSTM_H)
                     + (size_t)b0 * LSTM_H + j;
#pragma unroll
    for (int b = 0; b < 16; ++b) dst[(size_t)b * LSTM_H] = acc[b];
}

// ---------------- Phase B: the recurrence (MFMA) ----------------
// 64 blocks (1 batch each), 512 threads = 8 waves.
// Wave w, lane l: output j = 16*w + (l&15).
// B-frag (W, K=32 x N=16): lane l -> col n=l&15, k = 32*ks + 8*(l>>4) + e.
// A-frag (h, M=16 x K=32): all 16-lane groups read the same row-0 bytes ->
//   4-address wave broadcast, conflict-free (round-4: SQ_LDS_BANK_CONFLICT=0).
__global__ __launch_bounds__(512, 2) void lstm_phaseB(
    const float* __restrict__ Wf, const float* __restrict__ Wc,
    const float* __restrict__ Wfc, const float* __restrict__ bfc,
    const float* __restrict__ pre, float* __restrict__ state,
    float* __restrict__ out, int t0, int t1, int S)
{
    __shared__ __align__(16) short h_s[2][LSTM_H];   // bf16 h, double-buffered
    __shared__ float red_s[LSTM_H];

    const int b    = blockIdx.x;
    const int tid  = threadIdx.x;
    const int lane = tid & 63;
    const int w    = tid >> 6;          // wave 0..7
    const int jj   = 16 * w + (lane & 15);
    const int kb   = ((lane >> 4) & 3) * 8;   // k-sub-base within a kstep

    // ---- resident B-fragments: W h-part, bf16 ----
    bf16x8 bF[4], bC[4];
#pragma unroll
    for (int ks = 0; ks < 4; ++ks) {
        const float* rF = Wf + (size_t)jj * ROWW + LSTM_E + 32*ks + kb;
        const float* rC = Wc + (size_t)jj * ROWW + LSTM_E + 32*ks + kb;
        float4 f0 = *(const float4*)rF, f1 = *(const float4*)(rF + 4);
        float4 c0 = *(const float4*)rC, c1 = *(const float4*)(rC + 4);
        float ef[8] = {f0.x,f0.y,f0.z,f0.w,f1.x,f1.y,f1.z,f1.w};
        float ec[8] = {c0.x,c0.y,c0.z,c0.w,c1.x,c1.y,c1.z,c1.w};
#pragma unroll
        for (int e = 0; e < 8; ++e) {
            bF[ks][e] = f2bf(ef[e]);
            bC[ks][e] = f2bf(ec[e]);
        }
    }

    float c = 0.0f, h_last = 0.0f;
    if (t0 == 0) {
        if (tid < LSTM_H) h_s[0][tid] = 0;
    } else {
        if (tid < LSTM_H) h_s[0][tid] = f2bf(state[(size_t)b * LSTM_H + tid]);
        c = state[LSTM_B * LSTM_H + (size_t)b * LSTM_H + jj];
    }

    // pre stream, 2-deep prefetch (all lanes; lanes>=16 duplicate, coalesced)
    const float* prepF = pre + (size_t)b * LSTM_H + jj;        // [t][g=0][b][j]
    const float* prepC = prepF + LSTM_B * LSTM_H;              // g=1
    const int NT = t1 - t0;
    float pf0 = prepF[0], pc0 = prepC[0];
    float pf1 = 0.f, pc1 = 0.f;
    if (NT > 1) { pf1 = prepF[TSTRIDE]; pc1 = prepC[TSTRIDE]; }
    __syncthreads();

    const f32x4 zz = {0.f, 0.f, 0.f, 0.f};
    int tpf = 2;   // next prefetch slot (step index)

    // One timestep: reads h_s[CUR], writes h_s[NXT]. MFMAs chained through C.
#define STEP_BODY(CUR, NXT)                                                     \
    do {                                                                        \
        const short* hb = &h_s[CUR][0];                                         \
        bf16x8 a0 = *(const bf16x8*)(hb + 0*32 + kb);                           \
        bf16x8 a1 = *(const bf16x8*)(hb + 1*32 + kb);                           \
        bf16x8 a2 = *(const bf16x8*)(hb + 2*32 + kb);                           \
        bf16x8 a3 = *(const bf16x8*)(hb + 3*32 + kb);                           \
        float af_in = pf0, ac_in = pc0;                                         \
        pf0 = pf1; pc0 = pc1;                                                   \
        if (tpf < NT) { pf1 = prepF[(size_t)tpf * TSTRIDE];                     \
                        pc1 = prepC[(size_t)tpf * TSTRIDE]; }                   \
        ++tpf;                                                                  \
        f32x4 fa = __builtin_amdgcn_mfma_f32_16x16x32_bf16(a0, bF[0], zz, 0,0,0);\
        f32x4 ga = __builtin_amdgcn_mfma_f32_16x16x32_bf16(a0, bC[0], zz, 0,0,0);\
        fa = __builtin_amdgcn_mfma_f32_16x16x32_bf16(a1, bF[1], fa, 0,0,0);     \
        ga = __builtin_amdgcn_mfma_f32_16x16x32_bf16(a1, bC[1], ga, 0,0,0);     \
        fa = __builtin_amdgcn_mfma_f32_16x16x32_bf16(a2, bF[2], fa, 0,0,0);     \
        ga = __builtin_amdgcn_mfma_f32_16x16x32_bf16(a2, bC[2], ga, 0,0,0);     \
        fa = __builtin_amdgcn_mfma_f32_16x16x32_bf16(a3, bF[3], fa, 0,0,0);     \
        ga = __builtin_amdgcn_mfma_f32_16x16x32_bf16(a3, bC[3], ga, 0,0,0);     \
        float af = af_in + fa[0];                                               \
        float ac = ac_in + ga[0];                                               \
        float gg = sigmoidf_(af);                                               \
        float ct = tanh_fast(ac);                                               \
        c = gg * (c + ct);                                                      \
        float hn = gg * tanh_fast(c);                                           \
        h_last = hn;                                                            \
        if (lane < 16) h_s[NXT][jj] = f2bf_hw(hn);                              \
        __syncthreads();                                                        \
    } while (0)

    int t = 0;
    for (; t + 1 < NT; t += 2) {
        STEP_BODY(0, 1);
        STEP_BODY(1, 0);
    }
    int cur = 0;
    if (t < NT) { STEP_BODY(0, 1); cur = 1; }
#undef STEP_BODY

    if (t1 == S) {
        if (lane < 16) red_s[jj] = h_last * Wfc[jj];
        __syncthreads();
        if (tid < 64) {
            float s = red_s[tid] + red_s[tid + 64];
            s += __shfl_down(s, 32, 64);
            s += __shfl_down(s, 16, 64);
            s += __shfl_down(s, 8, 64);
            s += __shfl_down(s, 4, 64);
            s += __shfl_down(s, 2, 64);
            s += __shfl_down(s, 1, 64);
            if (tid == 0) out[b] = sigmoidf_(s + bfc[0]);
        }
    } else {
        if (lane < 16) {
            state[(size_t)b * LSTM_H + jj] = h_last;
            state[LSTM_B * LSTM_H + (size_t)b * LSTM_H + jj] = c;
        }
        (void)cur;
    }
}

extern "C" void kernel_launch(void* const* d_in, const int* in_sizes, int n_in,
                              void* d_out, int out_size, void* d_ws, size_t ws_size,
                              hipStream_t stream) {
    const int*   x   = (const int*)d_in[0];
    const float* emb = (const float*)d_in[1];
    const float* Wf  = (const float*)d_in[2];
    const float* bf  = (const float*)d_in[3];
    const float* Wc  = (const float*)d_in[4];
    const float* bc  = (const float*)d_in[5];
    const float* Wfc = (const float*)d_in[6];
    const float* bfc = (const float*)d_in[7];
    float* out = (float*)d_out;

    const int S = in_sizes[0] / LSTM_B;           // 2048

    float* state = (float*)d_ws;                              // h[64][128], c[64][128]
    float* pre   = state + (size_t)2 * LSTM_B * LSTM_H;       // + 64KB

    const size_t state_bytes = (size_t)2 * LSTM_B * LSTM_H * sizeof(float);
    const size_t per_t_bytes = (size_t)TSTRIDE * sizeof(float);   // 64 KB per step
    size_t avail = (ws_size > state_bytes) ? (ws_size - state_bytes) : 0;
    int CH = (int)(avail / per_t_bytes);
    if (CH > S) CH = S;
    if (CH < 1) CH = 1;   // requires ws_size >= 128KB + state

    for (int t0 = 0; t0 < S; t0 += CH) {
        const int t1 = (t0 + CH < S) ? (t0 + CH) : S;
        lstm_phaseA<<<(t1 - t0) * 4, 256, 0, stream>>>(x, emb, Wf, bf, Wc, bc,
                                                       pre, t0, S);
        lstm_phaseB<<<LSTM_B, 512, 0, stream>>>(Wf, Wc, Wfc, bfc, pre, state,
                                                out, t0, t1, S);
    }
}

// Round 8
// 696.753 us; speedup vs baseline: 1.6961x; 1.1975x over previous
//
#include <hip/hip_runtime.h>
#include <hip/hip_bf16.h>

// LSTM classifier: B=64, S=2048, E=H=128, OUT=1.
// Phase A (parallel, MFMA): pre[t][g][b][j] = bias[g][j] + emb[x[b,t]] . W_g[j][0:128]
//   as a tall GEMM: M = S*64 rows (r = (t-t0)*64 + b), N = 256 (2 gates x 128 j),
//   K = 128. A = emb rows in LDS as bf16 hi+lo planes (fp32-grade),
//   B = W E-columns as resident bf16 fragments, bias folded into acc init.
//   Round-7 phaseA ran the same GEMM on the fp32 vector pipe at ~104 TF
//   (~170 us); MFMA + HBM floor (134 MB pre-write + 67 MB gather) ~= 50 us.
// Phase B: byte-identical to round 7 (663 us, step ~775 cyc, issue-bound).

#define LSTM_B 64
#define LSTM_E 128
#define LSTM_H 128
#define ROWW   256           // E+H, weight row width
#define TSTRIDE (2*LSTM_B*LSTM_H)   // floats per timestep in pre buffer

typedef __attribute__((ext_vector_type(8))) short bf16x8;
typedef __attribute__((ext_vector_type(4))) float f32x4;

__device__ __forceinline__ float fast_rcp(float x) {
    return __builtin_amdgcn_rcpf(x);
}
__device__ __forceinline__ float sigmoidf_(float x) {
    return fast_rcp(1.0f + __expf(-x));
}
__device__ __forceinline__ float tanh_fast(float x) {
    float ax = fabsf(x);
    float t = __expf(-2.0f * ax);          // in (0,1], no overflow
    float r = (1.0f - t) * fast_rcp(1.0f + t);
    return copysignf(r, x);
}
__device__ __forceinline__ short f2bf(float f) {   // round-to-nearest-even
    union { float f; unsigned u; } v; v.f = f;
    unsigned r = (v.u + 0x7FFFu + ((v.u >> 16) & 1u)) >> 16;
    return (short)r;
}
__device__ __forceinline__ float bf2f(short s) {
    union { unsigned u; float f; } v; v.u = ((unsigned)(unsigned short)s) << 16;
    return v.f;
}
__device__ __forceinline__ short f2bf_hw(float f) {  // v_cvt_pk_bf16_f32 (RNE)
    unsigned r;
    float z = 0.0f;
    asm("v_cvt_pk_bf16_f32 %0, %1, %2" : "=v"(r) : "v"(f), "v"(z));
    return (short)(r & 0xFFFFu);
}

// ---------------- Phase A: input projections, MFMA GEMM ----------------
// Block: 128 rows x 256 cols, 512 threads = 8 waves.
// Wave w covers cols {16w..16w+15} (gate f, j=16w+(l&15)) and +128 (gate c).
// A LDS: [128][136] bf16 hi + lo planes; +16B row pad -> 2-way (free) banks.
// Fragment mapping (verified by phaseB rounds 4-7, absmax 0.0):
//   B-frag: col n = l&15, k = 32*ks + 8*(l>>4) + e.
//   A-frag: row m_local = l&15, same k.  C: col = l&15, row = (l>>4)*4 + i.
__global__ __launch_bounds__(512, 2) void lstm_phaseA(
    const int* __restrict__ x, const float* __restrict__ emb,
    const float* __restrict__ Wf, const float* __restrict__ bf,
    const float* __restrict__ Wc, const float* __restrict__ bc,
    float* __restrict__ pre, int t0, int t1, int S)
{
    __shared__ __align__(16) short a_hi[128][136];
    __shared__ __align__(16) short a_lo[128][136];
    __shared__ int idx_s[128];

    const int tid  = threadIdx.x;
    const int lane = tid & 63;
    const int w    = tid >> 6;
    const int r0   = blockIdx.x * 128;
    const int total_rows = (t1 - t0) * LSTM_B;
    const int nrows = (total_rows - r0 < 128) ? (total_rows - r0) : 128;

    if (tid < 128 && tid < nrows) {
        const int r = r0 + tid;
        idx_s[tid] = x[(size_t)(r & 63) * S + t0 + (r >> 6)];
    }
    __syncthreads();

    {   // gather emb rows -> bf16 hi/lo; 4 threads per row, 32 floats each
        const int row  = tid >> 2;
        const int part = (tid & 3) * 32;
        if (row < nrows) {
            const float* src = emb + (size_t)idx_s[row] * LSTM_E + part;
            short* dh = &a_hi[row][part];
            short* dl = &a_lo[row][part];
#pragma unroll
            for (int q = 0; q < 8; ++q) {
                float4 v = *(const float4*)(src + 4*q);
                short h0 = f2bf(v.x), h1 = f2bf(v.y), h2 = f2bf(v.z), h3 = f2bf(v.w);
                dh[4*q+0] = h0; dh[4*q+1] = h1; dh[4*q+2] = h2; dh[4*q+3] = h3;
                dl[4*q+0] = f2bf(v.x - bf2f(h0));
                dl[4*q+1] = f2bf(v.y - bf2f(h1));
                dl[4*q+2] = f2bf(v.z - bf2f(h2));
                dl[4*q+3] = f2bf(v.w - bf2f(h3));
            }
        }
    }

    // resident B-fragments: W E-part (cols 0..127), bf16
    const int jj = 16 * w + (lane & 15);
    const int kb = ((lane >> 4) & 3) * 8;
    bf16x8 bFr[4], bCr[4];
#pragma unroll
    for (int ks = 0; ks < 4; ++ks) {
        const float* rF = Wf + (size_t)jj * ROWW + 32*ks + kb;
        const float* rC = Wc + (size_t)jj * ROWW + 32*ks + kb;
        float4 f0 = *(const float4*)rF, f1 = *(const float4*)(rF + 4);
        float4 c0 = *(const float4*)rC, c1 = *(const float4*)(rC + 4);
        float ef[8] = {f0.x,f0.y,f0.z,f0.w,f1.x,f1.y,f1.z,f1.w};
        float ec[8] = {c0.x,c0.y,c0.z,c0.w,c1.x,c1.y,c1.z,c1.w};
#pragma unroll
        for (int e = 0; e < 8; ++e) { bFr[ks][e] = f2bf(ef[e]); bCr[ks][e] = f2bf(ec[e]); }
    }
    const float biasF = bf[jj], biasC = bc[jj];
    __syncthreads();

    f32x4 accF[8], accC[8];
#pragma unroll
    for (int m = 0; m < 8; ++m) {
        accF[m] = (f32x4){biasF, biasF, biasF, biasF};
        accC[m] = (f32x4){biasC, biasC, biasC, biasC};
    }

#pragma unroll
    for (int m = 0; m < 8; ++m) {
        const int ar = m * 16 + (lane & 15);
#pragma unroll
        for (int ks = 0; ks < 4; ++ks) {
            bf16x8 ah = *(const bf16x8*)&a_hi[ar][32*ks + kb];
            bf16x8 al = *(const bf16x8*)&a_lo[ar][32*ks + kb];
            accF[m] = __builtin_amdgcn_mfma_f32_16x16x32_bf16(ah, bFr[ks], accF[m], 0,0,0);
            accC[m] = __builtin_amdgcn_mfma_f32_16x16x32_bf16(ah, bCr[ks], accC[m], 0,0,0);
            accF[m] = __builtin_amdgcn_mfma_f32_16x16x32_bf16(al, bFr[ks], accF[m], 0,0,0);
            accC[m] = __builtin_amdgcn_mfma_f32_16x16x32_bf16(al, bCr[ks], accC[m], 0,0,0);
        }
    }

#pragma unroll
    for (int m = 0; m < 8; ++m) {
#pragma unroll
        for (int i = 0; i < 4; ++i) {
            const int rl = m * 16 + ((lane >> 4) & 3) * 4 + i;   // row in block
            if (rl < nrows) {
                const int r = r0 + rl;
                float* dst = pre + (size_t)(r >> 6) * TSTRIDE
                                 + (size_t)(r & 63) * LSTM_H + jj;
                dst[0]                 = accF[m][i];   // gate f plane
                dst[LSTM_B * LSTM_H]   = accC[m][i];   // gate c plane
            }
        }
    }
}

// ---------------- Phase B: the recurrence (MFMA) — unchanged from round 7 ----
__global__ __launch_bounds__(512, 2) void lstm_phaseB(
    const float* __restrict__ Wf, const float* __restrict__ Wc,
    const float* __restrict__ Wfc, const float* __restrict__ bfc,
    const float* __restrict__ pre, float* __restrict__ state,
    float* __restrict__ out, int t0, int t1, int S)
{
    __shared__ __align__(16) short h_s[2][LSTM_H];   // bf16 h, double-buffered
    __shared__ float red_s[LSTM_H];

    const int b    = blockIdx.x;
    const int tid  = threadIdx.x;
    const int lane = tid & 63;
    const int w    = tid >> 6;          // wave 0..7
    const int jj   = 16 * w + (lane & 15);
    const int kb   = ((lane >> 4) & 3) * 8;   // k-sub-base within a kstep

    // ---- resident B-fragments: W h-part, bf16 ----
    bf16x8 bF[4], bC[4];
#pragma unroll
    for (int ks = 0; ks < 4; ++ks) {
        const float* rF = Wf + (size_t)jj * ROWW + LSTM_E + 32*ks + kb;
        const float* rC = Wc + (size_t)jj * ROWW + LSTM_E + 32*ks + kb;
        float4 f0 = *(const float4*)rF, f1 = *(const float4*)(rF + 4);
        float4 c0 = *(const float4*)rC, c1 = *(const float4*)(rC + 4);
        float ef[8] = {f0.x,f0.y,f0.z,f0.w,f1.x,f1.y,f1.z,f1.w};
        float ec[8] = {c0.x,c0.y,c0.z,c0.w,c1.x,c1.y,c1.z,c1.w};
#pragma unroll
        for (int e = 0; e < 8; ++e) {
            bF[ks][e] = f2bf(ef[e]);
            bC[ks][e] = f2bf(ec[e]);
        }
    }

    float c = 0.0f, h_last = 0.0f;
    if (t0 == 0) {
        if (tid < LSTM_H) h_s[0][tid] = 0;
    } else {
        if (tid < LSTM_H) h_s[0][tid] = f2bf(state[(size_t)b * LSTM_H + tid]);
        c = state[LSTM_B * LSTM_H + (size_t)b * LSTM_H + jj];
    }

    // pre stream, 2-deep prefetch (all lanes; lanes>=16 duplicate, coalesced)
    const float* prepF = pre + (size_t)b * LSTM_H + jj;        // [t][g=0][b][j]
    const float* prepC = prepF + LSTM_B * LSTM_H;              // g=1
    const int NT = t1 - t0;
    float pf0 = prepF[0], pc0 = prepC[0];
    float pf1 = 0.f, pc1 = 0.f;
    if (NT > 1) { pf1 = prepF[TSTRIDE]; pc1 = prepC[TSTRIDE]; }
    __syncthreads();

    const f32x4 zz = {0.f, 0.f, 0.f, 0.f};
    int tpf = 2;   // next prefetch slot (step index)

#define STEP_BODY(CUR, NXT)                                                     \
    do {                                                                        \
        const short* hb = &h_s[CUR][0];                                         \
        bf16x8 a0 = *(const bf16x8*)(hb + 0*32 + kb);                           \
        bf16x8 a1 = *(const bf16x8*)(hb + 1*32 + kb);                           \
        bf16x8 a2 = *(const bf16x8*)(hb + 2*32 + kb);                           \
        bf16x8 a3 = *(const bf16x8*)(hb + 3*32 + kb);                           \
        float af_in = pf0, ac_in = pc0;                                         \
        pf0 = pf1; pc0 = pc1;                                                   \
        if (tpf < NT) { pf1 = prepF[(size_t)tpf * TSTRIDE];                     \
                        pc1 = prepC[(size_t)tpf * TSTRIDE]; }                   \
        ++tpf;                                                                  \
        f32x4 fa = __builtin_amdgcn_mfma_f32_16x16x32_bf16(a0, bF[0], zz, 0,0,0);\
        f32x4 ga = __builtin_amdgcn_mfma_f32_16x16x32_bf16(a0, bC[0], zz, 0,0,0);\
        fa = __builtin_amdgcn_mfma_f32_16x16x32_bf16(a1, bF[1], fa, 0,0,0);     \
        ga = __builtin_amdgcn_mfma_f32_16x16x32_bf16(a1, bC[1], ga, 0,0,0);     \
        fa = __builtin_amdgcn_mfma_f32_16x16x32_bf16(a2, bF[2], fa, 0,0,0);     \
        ga = __builtin_amdgcn_mfma_f32_16x16x32_bf16(a2, bC[2], ga, 0,0,0);     \
        fa = __builtin_amdgcn_mfma_f32_16x16x32_bf16(a3, bF[3], fa, 0,0,0);     \
        ga = __builtin_amdgcn_mfma_f32_16x16x32_bf16(a3, bC[3], ga, 0,0,0);     \
        float af = af_in + fa[0];                                               \
        float ac = ac_in + ga[0];                                               \
        float gg = sigmoidf_(af);                                               \
        float ct = tanh_fast(ac);                                               \
        c = gg * (c + ct);                                                      \
        float hn = gg * tanh_fast(c);                                           \
        h_last = hn;                                                            \
        if (lane < 16) h_s[NXT][jj] = f2bf_hw(hn);                              \
        __syncthreads();                                                        \
    } while (0)

    int t = 0;
    for (; t + 1 < NT; t += 2) {
        STEP_BODY(0, 1);
        STEP_BODY(1, 0);
    }
    int cur = 0;
    if (t < NT) { STEP_BODY(0, 1); cur = 1; }
#undef STEP_BODY

    if (t1 == S) {
        if (lane < 16) red_s[jj] = h_last * Wfc[jj];
        __syncthreads();
        if (tid < 64) {
            float s = red_s[tid] + red_s[tid + 64];
            s += __shfl_down(s, 32, 64);
            s += __shfl_down(s, 16, 64);
            s += __shfl_down(s, 8, 64);
            s += __shfl_down(s, 4, 64);
            s += __shfl_down(s, 2, 64);
            s += __shfl_down(s, 1, 64);
            if (tid == 0) out[b] = sigmoidf_(s + bfc[0]);
        }
    } else {
        if (lane < 16) {
            state[(size_t)b * LSTM_H + jj] = h_last;
            state[LSTM_B * LSTM_H + (size_t)b * LSTM_H + jj] = c;
        }
        (void)cur;
    }
}

extern "C" void kernel_launch(void* const* d_in, const int* in_sizes, int n_in,
                              void* d_out, int out_size, void* d_ws, size_t ws_size,
                              hipStream_t stream) {
    const int*   x   = (const int*)d_in[0];
    const float* emb = (const float*)d_in[1];
    const float* Wf  = (const float*)d_in[2];
    const float* bf  = (const float*)d_in[3];
    const float* Wc  = (const float*)d_in[4];
    const float* bc  = (const float*)d_in[5];
    const float* Wfc = (const float*)d_in[6];
    const float* bfc = (const float*)d_in[7];
    float* out = (float*)d_out;

    const int S = in_sizes[0] / LSTM_B;           // 2048

    float* state = (float*)d_ws;                              // h[64][128], c[64][128]
    float* pre   = state + (size_t)2 * LSTM_B * LSTM_H;       // + 64KB

    const size_t state_bytes = (size_t)2 * LSTM_B * LSTM_H * sizeof(float);
    const size_t per_t_bytes = (size_t)TSTRIDE * sizeof(float);   // 64 KB per step
    size_t avail = (ws_size > state_bytes) ? (ws_size - state_bytes) : 0;
    int CH = (int)(avail / per_t_bytes);
    if (CH > S) CH = S;
    if (CH < 1) CH = 1;   // requires ws_size >= 128KB + state

    for (int t0 = 0; t0 < S; t0 += CH) {
        const int t1 = (t0 + CH < S) ? (t0 + CH) : S;
        const int nblocksA = ((t1 - t0) * LSTM_B + 127) / 128;
        lstm_phaseA<<<nblocksA, 512, 0, stream>>>(x, emb, Wf, bf, Wc, bc,
                                                  pre, t0, t1, S);
        lstm_phaseB<<<LSTM_B, 512, 0, stream>>>(Wf, Wc, Wfc, bfc, pre, state,
                                                out, t0, t1, S);
    }
}

// Round 9
// 695.878 us; speedup vs baseline: 1.6982x; 1.0013x over previous
//
#include <hip/hip_runtime.h>
#include <hip/hip_bf16.h>

// LSTM classifier: B=64, S=2048, E=H=128, OUT=1.
// Phase A (parallel, MFMA GEMM): pre[t][g][b][j] = bias + emb[x[b,t]].W_g[j][:128]
// Phase B (sequential, 1 WG/batch, 8 waves): h-matmul via mfma 16x16x32 bf16,
//   M=1, resident bf16 B-fragments. Step ~775 cyc; floor: 256 matrix + ~240
//   VALU + serial chain. Round-9: chain depth 4->2 (4 indep + 4 dep MFMAs),
//   rotation-free 2-body prefetch (dedicated regs, 32-bit offsets),
//   phaseA staging via ds_write_b128.

#define LSTM_B 64
#define LSTM_E 128
#define LSTM_H 128
#define ROWW   256           // E+H, weight row width
#define TSTRIDE (2*LSTM_B*LSTM_H)   // floats per timestep in pre buffer

typedef __attribute__((ext_vector_type(8))) short bf16x8;
typedef __attribute__((ext_vector_type(4))) float f32x4;

__device__ __forceinline__ float fast_rcp(float x) {
    return __builtin_amdgcn_rcpf(x);
}
__device__ __forceinline__ float sigmoidf_(float x) {
    return fast_rcp(1.0f + __expf(-x));
}
__device__ __forceinline__ float tanh_fast(float x) {
    float ax = fabsf(x);
    float t = __expf(-2.0f * ax);          // in (0,1], no overflow
    float r = (1.0f - t) * fast_rcp(1.0f + t);
    return copysignf(r, x);
}
__device__ __forceinline__ short f2bf(float f) {   // round-to-nearest-even
    union { float f; unsigned u; } v; v.f = f;
    unsigned r = (v.u + 0x7FFFu + ((v.u >> 16) & 1u)) >> 16;
    return (short)r;
}
__device__ __forceinline__ float bf2f(short s) {
    union { unsigned u; float f; } v; v.u = ((unsigned)(unsigned short)s) << 16;
    return v.f;
}
__device__ __forceinline__ short f2bf_hw(float f) {  // v_cvt_pk_bf16_f32 (RNE)
    unsigned r;
    float z = 0.0f;
    asm("v_cvt_pk_bf16_f32 %0, %1, %2" : "=v"(r) : "v"(f), "v"(z));
    return (short)(r & 0xFFFFu);
}

// ---------------- Phase A: input projections, MFMA GEMM ----------------
// Block: 128 rows x 256 cols, 512 threads = 8 waves.
__global__ __launch_bounds__(512, 2) void lstm_phaseA(
    const int* __restrict__ x, const float* __restrict__ emb,
    const float* __restrict__ Wf, const float* __restrict__ bf,
    const float* __restrict__ Wc, const float* __restrict__ bc,
    float* __restrict__ pre, int t0, int t1, int S)
{
    __shared__ __align__(16) short a_hi[128][136];
    __shared__ __align__(16) short a_lo[128][136];
    __shared__ int idx_s[128];

    const int tid  = threadIdx.x;
    const int lane = tid & 63;
    const int w    = tid >> 6;
    const int r0   = blockIdx.x * 128;
    const int total_rows = (t1 - t0) * LSTM_B;
    const int nrows = (total_rows - r0 < 128) ? (total_rows - r0) : 128;

    if (tid < 128 && tid < nrows) {
        const int r = r0 + tid;
        idx_s[tid] = x[(size_t)(r & 63) * S + t0 + (r >> 6)];
    }
    __syncthreads();

    {   // gather emb rows -> bf16 hi/lo; 4 threads/row, 32 floats each,
        // staged in regs then stored as 4+4 ds_write_b128 (round-8 used 64
        // scalar b16 writes -> 2.6M bank conflicts).
        const int row  = tid >> 2;
        const int part = (tid & 3) * 32;
        if (row < nrows) {
            const float* src = emb + (size_t)idx_s[row] * LSTM_E + part;
            bf16x8 vh[4], vl[4];
#pragma unroll
            for (int q = 0; q < 4; ++q) {
                float4 u = *(const float4*)(src + 8*q);
                float4 v = *(const float4*)(src + 8*q + 4);
                float e[8] = {u.x,u.y,u.z,u.w,v.x,v.y,v.z,v.w};
#pragma unroll
                for (int k = 0; k < 8; ++k) {
                    short h = f2bf(e[k]);
                    vh[q][k] = h;
                    vl[q][k] = f2bf(e[k] - bf2f(h));
                }
            }
#pragma unroll
            for (int q = 0; q < 4; ++q) {
                *(bf16x8*)&a_hi[row][part + 8*q] = vh[q];
                *(bf16x8*)&a_lo[row][part + 8*q] = vl[q];
            }
        }
    }

    // resident B-fragments: W E-part (cols 0..127), bf16
    const int jj = 16 * w + (lane & 15);
    const int kb = ((lane >> 4) & 3) * 8;
    bf16x8 bFr[4], bCr[4];
#pragma unroll
    for (int ks = 0; ks < 4; ++ks) {
        const float* rF = Wf + (size_t)jj * ROWW + 32*ks + kb;
        const float* rC = Wc + (size_t)jj * ROWW + 32*ks + kb;
        float4 f0 = *(const float4*)rF, f1 = *(const float4*)(rF + 4);
        float4 c0 = *(const float4*)rC, c1 = *(const float4*)(rC + 4);
        float ef[8] = {f0.x,f0.y,f0.z,f0.w,f1.x,f1.y,f1.z,f1.w};
        float ec[8] = {c0.x,c0.y,c0.z,c0.w,c1.x,c1.y,c1.z,c1.w};
#pragma unroll
        for (int e = 0; e < 8; ++e) { bFr[ks][e] = f2bf(ef[e]); bCr[ks][e] = f2bf(ec[e]); }
    }
    const float biasF = bf[jj], biasC = bc[jj];
    __syncthreads();

    f32x4 accF[8], accC[8];
#pragma unroll
    for (int m = 0; m < 8; ++m) {
        accF[m] = (f32x4){biasF, biasF, biasF, biasF};
        accC[m] = (f32x4){biasC, biasC, biasC, biasC};
    }

#pragma unroll
    for (int m = 0; m < 8; ++m) {
        const int ar = m * 16 + (lane & 15);
#pragma unroll
        for (int ks = 0; ks < 4; ++ks) {
            bf16x8 ah = *(const bf16x8*)&a_hi[ar][32*ks + kb];
            bf16x8 al = *(const bf16x8*)&a_lo[ar][32*ks + kb];
            accF[m] = __builtin_amdgcn_mfma_f32_16x16x32_bf16(ah, bFr[ks], accF[m], 0,0,0);
            accC[m] = __builtin_amdgcn_mfma_f32_16x16x32_bf16(ah, bCr[ks], accC[m], 0,0,0);
            accF[m] = __builtin_amdgcn_mfma_f32_16x16x32_bf16(al, bFr[ks], accF[m], 0,0,0);
            accC[m] = __builtin_amdgcn_mfma_f32_16x16x32_bf16(al, bCr[ks], accC[m], 0,0,0);
        }
    }

#pragma unroll
    for (int m = 0; m < 8; ++m) {
#pragma unroll
        for (int i = 0; i < 4; ++i) {
            const int rl = m * 16 + ((lane >> 4) & 3) * 4 + i;   // row in block
            if (rl < nrows) {
                const int r = r0 + rl;
                float* dst = pre + (size_t)(r >> 6) * TSTRIDE
                                 + (size_t)(r & 63) * LSTM_H + jj;
                dst[0]                 = accF[m][i];   // gate f plane
                dst[LSTM_B * LSTM_H]   = accC[m][i];   // gate c plane
            }
        }
    }
}

// ---------------- Phase B: the recurrence (MFMA) ----------------
// 64 blocks (1 batch each), 512 threads = 8 waves.
// Wave w, lane l: output j = 16*w + (l&15).
// B-frag: col n=l&15, k = 32*ks + 8*(l>>4) + e.  A-frag: broadcast row 0.
__global__ __launch_bounds__(512, 2) void lstm_phaseB(
    const float* __restrict__ Wf, const float* __restrict__ Wc,
    const float* __restrict__ Wfc, const float* __restrict__ bfc,
    const float* __restrict__ pre, float* __restrict__ state,
    float* __restrict__ out, int t0, int t1, int S)
{
    __shared__ __align__(16) short h_s[2][LSTM_H];   // bf16 h, double-buffered
    __shared__ float red_s[LSTM_H];

    const int b    = blockIdx.x;
    const int tid  = threadIdx.x;
    const int lane = tid & 63;
    const int w    = tid >> 6;          // wave 0..7
    const int jj   = 16 * w + (lane & 15);
    const int kb   = ((lane >> 4) & 3) * 8;   // k-sub-base within a kstep

    // ---- resident B-fragments: W h-part, bf16 ----
    bf16x8 bF[4], bC[4];
#pragma unroll
    for (int ks = 0; ks < 4; ++ks) {
        const float* rF = Wf + (size_t)jj * ROWW + LSTM_E + 32*ks + kb;
        const float* rC = Wc + (size_t)jj * ROWW + LSTM_E + 32*ks + kb;
        float4 f0 = *(const float4*)rF, f1 = *(const float4*)(rF + 4);
        float4 c0 = *(const float4*)rC, c1 = *(const float4*)(rC + 4);
        float ef[8] = {f0.x,f0.y,f0.z,f0.w,f1.x,f1.y,f1.z,f1.w};
        float ec[8] = {c0.x,c0.y,c0.z,c0.w,c1.x,c1.y,c1.z,c1.w};
#pragma unroll
        for (int e = 0; e < 8; ++e) {
            bF[ks][e] = f2bf(ef[e]);
            bC[ks][e] = f2bf(ec[e]);
        }
    }

    float c = 0.0f, h_last = 0.0f;
    if (t0 == 0) {
        if (tid < LSTM_H) h_s[0][tid] = 0;
    } else {
        if (tid < LSTM_H) h_s[0][tid] = f2bf(state[(size_t)b * LSTM_H + tid]);
        c = state[LSTM_B * LSTM_H + (size_t)b * LSTM_H + jj];
    }

    // pre stream, 2-deep prefetch; 2-body unroll with dedicated registers
    // (no rotation movs), 32-bit element offsets (no size_t mul per step).
    const float* prepF = pre + (size_t)b * LSTM_H + jj;        // [t][g=0][b][j]
    const float* prepC = prepF + LSTM_B * LSTM_H;              // g=1
    const int NT = t1 - t0;
    float pf0 = prepF[0], pc0 = prepC[0];
    float pf1 = 0.f, pc1 = 0.f;
    if (NT > 1) { pf1 = prepF[TSTRIDE]; pc1 = prepC[TSTRIDE]; }
    int off0 = 2 * TSTRIDE;   // body0 refill: even steps t+2
    int off1 = 3 * TSTRIDE;   // body1 refill: odd steps t+3
    __syncthreads();

    const f32x4 zz = {0.f, 0.f, 0.f, 0.f};

    // One timestep. MFMAs: 4 independent then 4 dependent (chain depth 2).
#define STEP_BODY(CUR, NXT, PF, PC, OFF, TLD)                                   \
    do {                                                                        \
        const short* hb = &h_s[CUR][0];                                         \
        bf16x8 a0 = *(const bf16x8*)(hb + 0*32 + kb);                           \
        bf16x8 a1 = *(const bf16x8*)(hb + 1*32 + kb);                           \
        bf16x8 a2 = *(const bf16x8*)(hb + 2*32 + kb);                           \
        bf16x8 a3 = *(const bf16x8*)(hb + 3*32 + kb);                           \
        float af_in = PF, ac_in = PC;                                           \
        if ((TLD) < NT) { PF = prepF[OFF]; PC = prepC[OFF]; }                   \
        OFF += 2 * TSTRIDE;                                                     \
        f32x4 fa = __builtin_amdgcn_mfma_f32_16x16x32_bf16(a0, bF[0], zz, 0,0,0);\
        f32x4 ga = __builtin_amdgcn_mfma_f32_16x16x32_bf16(a0, bC[0], zz, 0,0,0);\
        f32x4 fb = __builtin_amdgcn_mfma_f32_16x16x32_bf16(a2, bF[2], zz, 0,0,0);\
        f32x4 gb = __builtin_amdgcn_mfma_f32_16x16x32_bf16(a2, bC[2], zz, 0,0,0);\
        fa = __builtin_amdgcn_mfma_f32_16x16x32_bf16(a1, bF[1], fa, 0,0,0);     \
        ga = __builtin_amdgcn_mfma_f32_16x16x32_bf16(a1, bC[1], ga, 0,0,0);     \
        fb = __builtin_amdgcn_mfma_f32_16x16x32_bf16(a3, bF[3], fb, 0,0,0);     \
        gb = __builtin_amdgcn_mfma_f32_16x16x32_bf16(a3, bC[3], gb, 0,0,0);     \
        float af = af_in + (fa[0] + fb[0]);                                     \
        float ac = ac_in + (ga[0] + gb[0]);                                     \
        float gg = sigmoidf_(af);                                               \
        float ct = tanh_fast(ac);                                               \
        c = gg * (c + ct);                                                      \
        float hn = gg * tanh_fast(c);                                           \
        h_last = hn;                                                            \
        if (lane < 16) h_s[NXT][jj] = f2bf_hw(hn);                              \
        __syncthreads();                                                        \
    } while (0)

    int t = 0;
    for (; t + 1 < NT; t += 2) {
        STEP_BODY(0, 1, pf0, pc0, off0, t + 2);
        STEP_BODY(1, 0, pf1, pc1, off1, t + 3);
    }
    if (t < NT) { STEP_BODY(0, 1, pf0, pc0, off0, t + 2); }
#undef STEP_BODY

    if (t1 == S) {
        if (lane < 16) red_s[jj] = h_last * Wfc[jj];
        __syncthreads();
        if (tid < 64) {
            float s = red_s[tid] + red_s[tid + 64];
            s += __shfl_down(s, 32, 64);
            s += __shfl_down(s, 16, 64);
            s += __shfl_down(s, 8, 64);
            s += __shfl_down(s, 4, 64);
            s += __shfl_down(s, 2, 64);
            s += __shfl_down(s, 1, 64);
            if (tid == 0) out[b] = sigmoidf_(s + bfc[0]);
        }
    } else {
        if (lane < 16) {
            state[(size_t)b * LSTM_H + jj] = h_last;
            state[LSTM_B * LSTM_H + (size_t)b * LSTM_H + jj] = c;
        }
    }
}

extern "C" void kernel_launch(void* const* d_in, const int* in_sizes, int n_in,
                              void* d_out, int out_size, void* d_ws, size_t ws_size,
                              hipStream_t stream) {
    const int*   x   = (const int*)d_in[0];
    const float* emb = (const float*)d_in[1];
    const float* Wf  = (const float*)d_in[2];
    const float* bf  = (const float*)d_in[3];
    const float* Wc  = (const float*)d_in[4];
    const float* bc  = (const float*)d_in[5];
    const float* Wfc = (const float*)d_in[6];
    const float* bfc = (const float*)d_in[7];
    float* out = (float*)d_out;

    const int S = in_sizes[0] / LSTM_B;           // 2048

    float* state = (float*)d_ws;                              // h[64][128], c[64][128]
    float* pre   = state + (size_t)2 * LSTM_B * LSTM_H;       // + 64KB

    const size_t state_bytes = (size_t)2 * LSTM_B * LSTM_H * sizeof(float);
    const size_t per_t_bytes = (size_t)TSTRIDE * sizeof(float);   // 64 KB per step
    size_t avail = (ws_size > state_bytes) ? (ws_size - state_bytes) : 0;
    int CH = (int)(avail / per_t_bytes);
    if (CH > S) CH = S;
    if (CH < 1) CH = 1;   // requires ws_size >= 128KB + state

    for (int t0 = 0; t0 < S; t0 += CH) {
        const int t1 = (t0 + CH < S) ? (t0 + CH) : S;
        const int nblocksA = ((t1 - t0) * LSTM_B + 127) / 128;
        lstm_phaseA<<<nblocksA, 512, 0, stream>>>(x, emb, Wf, bf, Wc, bc,
                                                  pre, t0, t1, S);
        lstm_phaseB<<<LSTM_B, 512, 0, stream>>>(Wf, Wc, Wfc, bfc, pre, state,
                                                out, t0, t1, S);
    }
}

// Round 10
// 694.785 us; speedup vs baseline: 1.7009x; 1.0016x over previous
//
#include <hip/hip_runtime.h>
#include <hip/hip_bf16.h>

// LSTM classifier: B=64, S=2048, E=H=128, OUT=1.
// Phase A (parallel, MFMA GEMM): pre[t][g][b][j] = bias + emb[x[b,t]].W_g[j][:128]
// Phase B (sequential, 1 WG/batch, 8 waves): h-matmul via mfma 16x16x32 bf16,
//   M=1, resident bf16 B-fragments.
// Round-10 change (ONLY): step-end barrier no longer drains vmcnt.
//   __syncthreads() lowers to s_waitcnt vmcnt(0) lgkmcnt(0) + s_barrier, which
//   force-completes the in-flight HBM prefetch loads (~900 cyc latency) within
//   the issuing step (~775 cyc) -> ~200-350 cyc residual stall per step. This
//   also explains why deeper prefetch (r4) and VALU diets (r9) were neutral.
//   Replaced with builtin s_waitcnt(lgkmcnt(0) only) + s_barrier (no inline
//   asm, no "memory" clobber -- r5's regression came from clobber-pessimized
//   scheduling, not from the counted-vmcnt idea itself).

#define LSTM_B 64
#define LSTM_E 128
#define LSTM_H 128
#define ROWW   256           // E+H, weight row width
#define TSTRIDE (2*LSTM_B*LSTM_H)   // floats per timestep in pre buffer

typedef __attribute__((ext_vector_type(8))) short bf16x8;
typedef __attribute__((ext_vector_type(4))) float f32x4;

__device__ __forceinline__ float fast_rcp(float x) {
    return __builtin_amdgcn_rcpf(x);
}
__device__ __forceinline__ float sigmoidf_(float x) {
    return fast_rcp(1.0f + __expf(-x));
}
__device__ __forceinline__ float tanh_fast(float x) {
    float ax = fabsf(x);
    float t = __expf(-2.0f * ax);          // in (0,1], no overflow
    float r = (1.0f - t) * fast_rcp(1.0f + t);
    return copysignf(r, x);
}
__device__ __forceinline__ short f2bf(float f) {   // round-to-nearest-even
    union { float f; unsigned u; } v; v.f = f;
    unsigned r = (v.u + 0x7FFFu + ((v.u >> 16) & 1u)) >> 16;
    return (short)r;
}
__device__ __forceinline__ float bf2f(short s) {
    union { unsigned u; float f; } v; v.u = ((unsigned)(unsigned short)s) << 16;
    return v.f;
}
__device__ __forceinline__ short f2bf_hw(float f) {  // v_cvt_pk_bf16_f32 (RNE)
    unsigned r;
    float z = 0.0f;
    asm("v_cvt_pk_bf16_f32 %0, %1, %2" : "=v"(r) : "v"(f), "v"(z));
    return (short)(r & 0xFFFFu);
}

// Barrier that waits only on LDS ops (lgkmcnt(0)); vmcnt/expcnt untouched so
// global prefetch loads stay in flight across the barrier.
// waitcnt simm16: vmcnt[3:0]|[15:14]=63, expcnt[6:4]=7, lgkmcnt[11:8]=0 -> 0xC07F.
__device__ __forceinline__ void lds_only_barrier() {
    __builtin_amdgcn_s_waitcnt(0xC07F);
    __builtin_amdgcn_s_barrier();
}

// ---------------- Phase A: input projections, MFMA GEMM ----------------
// Block: 128 rows x 256 cols, 512 threads = 8 waves.
__global__ __launch_bounds__(512, 2) void lstm_phaseA(
    const int* __restrict__ x, const float* __restrict__ emb,
    const float* __restrict__ Wf, const float* __restrict__ bf,
    const float* __restrict__ Wc, const float* __restrict__ bc,
    float* __restrict__ pre, int t0, int t1, int S)
{
    __shared__ __align__(16) short a_hi[128][136];
    __shared__ __align__(16) short a_lo[128][136];
    __shared__ int idx_s[128];

    const int tid  = threadIdx.x;
    const int lane = tid & 63;
    const int w    = tid >> 6;
    const int r0   = blockIdx.x * 128;
    const int total_rows = (t1 - t0) * LSTM_B;
    const int nrows = (total_rows - r0 < 128) ? (total_rows - r0) : 128;

    if (tid < 128 && tid < nrows) {
        const int r = r0 + tid;
        idx_s[tid] = x[(size_t)(r & 63) * S + t0 + (r >> 6)];
    }
    __syncthreads();

    {   // gather emb rows -> bf16 hi/lo; 4 threads/row, 32 floats each,
        // staged in regs, stored as ds_write_b128.
        const int row  = tid >> 2;
        const int part = (tid & 3) * 32;
        if (row < nrows) {
            const float* src = emb + (size_t)idx_s[row] * LSTM_E + part;
            bf16x8 vh[4], vl[4];
#pragma unroll
            for (int q = 0; q < 4; ++q) {
                float4 u = *(const float4*)(src + 8*q);
                float4 v = *(const float4*)(src + 8*q + 4);
                float e[8] = {u.x,u.y,u.z,u.w,v.x,v.y,v.z,v.w};
#pragma unroll
                for (int k = 0; k < 8; ++k) {
                    short h = f2bf(e[k]);
                    vh[q][k] = h;
                    vl[q][k] = f2bf(e[k] - bf2f(h));
                }
            }
#pragma unroll
            for (int q = 0; q < 4; ++q) {
                *(bf16x8*)&a_hi[row][part + 8*q] = vh[q];
                *(bf16x8*)&a_lo[row][part + 8*q] = vl[q];
            }
        }
    }

    // resident B-fragments: W E-part (cols 0..127), bf16
    const int jj = 16 * w + (lane & 15);
    const int kb = ((lane >> 4) & 3) * 8;
    bf16x8 bFr[4], bCr[4];
#pragma unroll
    for (int ks = 0; ks < 4; ++ks) {
        const float* rF = Wf + (size_t)jj * ROWW + 32*ks + kb;
        const float* rC = Wc + (size_t)jj * ROWW + 32*ks + kb;
        float4 f0 = *(const float4*)rF, f1 = *(const float4*)(rF + 4);
        float4 c0 = *(const float4*)rC, c1 = *(const float4*)(rC + 4);
        float ef[8] = {f0.x,f0.y,f0.z,f0.w,f1.x,f1.y,f1.z,f1.w};
        float ec[8] = {c0.x,c0.y,c0.z,c0.w,c1.x,c1.y,c1.z,c1.w};
#pragma unroll
        for (int e = 0; e < 8; ++e) { bFr[ks][e] = f2bf(ef[e]); bCr[ks][e] = f2bf(ec[e]); }
    }
    const float biasF = bf[jj], biasC = bc[jj];
    __syncthreads();

    f32x4 accF[8], accC[8];
#pragma unroll
    for (int m = 0; m < 8; ++m) {
        accF[m] = (f32x4){biasF, biasF, biasF, biasF};
        accC[m] = (f32x4){biasC, biasC, biasC, biasC};
    }

#pragma unroll
    for (int m = 0; m < 8; ++m) {
        const int ar = m * 16 + (lane & 15);
#pragma unroll
        for (int ks = 0; ks < 4; ++ks) {
            bf16x8 ah = *(const bf16x8*)&a_hi[ar][32*ks + kb];
            bf16x8 al = *(const bf16x8*)&a_lo[ar][32*ks + kb];
            accF[m] = __builtin_amdgcn_mfma_f32_16x16x32_bf16(ah, bFr[ks], accF[m], 0,0,0);
            accC[m] = __builtin_amdgcn_mfma_f32_16x16x32_bf16(ah, bCr[ks], accC[m], 0,0,0);
            accF[m] = __builtin_amdgcn_mfma_f32_16x16x32_bf16(al, bFr[ks], accF[m], 0,0,0);
            accC[m] = __builtin_amdgcn_mfma_f32_16x16x32_bf16(al, bCr[ks], accC[m], 0,0,0);
        }
    }

#pragma unroll
    for (int m = 0; m < 8; ++m) {
#pragma unroll
        for (int i = 0; i < 4; ++i) {
            const int rl = m * 16 + ((lane >> 4) & 3) * 4 + i;   // row in block
            if (rl < nrows) {
                const int r = r0 + rl;
                float* dst = pre + (size_t)(r >> 6) * TSTRIDE
                                 + (size_t)(r & 63) * LSTM_H + jj;
                dst[0]                 = accF[m][i];   // gate f plane
                dst[LSTM_B * LSTM_H]   = accC[m][i];   // gate c plane
            }
        }
    }
}

// ---------------- Phase B: the recurrence (MFMA) ----------------
// 64 blocks (1 batch each), 512 threads = 8 waves.
// Wave w, lane l: output j = 16*w + (l&15).
// B-frag: col n=l&15, k = 32*ks + 8*(l>>4) + e.  A-frag: broadcast row 0.
__global__ __launch_bounds__(512, 2) void lstm_phaseB(
    const float* __restrict__ Wf, const float* __restrict__ Wc,
    const float* __restrict__ Wfc, const float* __restrict__ bfc,
    const float* __restrict__ pre, float* __restrict__ state,
    float* __restrict__ out, int t0, int t1, int S)
{
    __shared__ __align__(16) short h_s[2][LSTM_H];   // bf16 h, double-buffered
    __shared__ float red_s[LSTM_H];

    const int b    = blockIdx.x;
    const int tid  = threadIdx.x;
    const int lane = tid & 63;
    const int w    = tid >> 6;          // wave 0..7
    const int jj   = 16 * w + (lane & 15);
    const int kb   = ((lane >> 4) & 3) * 8;   // k-sub-base within a kstep

    // ---- resident B-fragments: W h-part, bf16 ----
    bf16x8 bF[4], bC[4];
#pragma unroll
    for (int ks = 0; ks < 4; ++ks) {
        const float* rF = Wf + (size_t)jj * ROWW + LSTM_E + 32*ks + kb;
        const float* rC = Wc + (size_t)jj * ROWW + LSTM_E + 32*ks + kb;
        float4 f0 = *(const float4*)rF, f1 = *(const float4*)(rF + 4);
        float4 c0 = *(const float4*)rC, c1 = *(const float4*)(rC + 4);
        float ef[8] = {f0.x,f0.y,f0.z,f0.w,f1.x,f1.y,f1.z,f1.w};
        float ec[8] = {c0.x,c0.y,c0.z,c0.w,c1.x,c1.y,c1.z,c1.w};
#pragma unroll
        for (int e = 0; e < 8; ++e) {
            bF[ks][e] = f2bf(ef[e]);
            bC[ks][e] = f2bf(ec[e]);
        }
    }

    float c = 0.0f, h_last = 0.0f;
    if (t0 == 0) {
        if (tid < LSTM_H) h_s[0][tid] = 0;
    } else {
        if (tid < LSTM_H) h_s[0][tid] = f2bf(state[(size_t)b * LSTM_H + tid]);
        c = state[LSTM_B * LSTM_H + (size_t)b * LSTM_H + jj];
    }

    // pre stream, 2-deep prefetch; 2-body unroll, dedicated registers,
    // 32-bit element offsets.
    const float* prepF = pre + (size_t)b * LSTM_H + jj;        // [t][g=0][b][j]
    const float* prepC = prepF + LSTM_B * LSTM_H;              // g=1
    const int NT = t1 - t0;
    float pf0 = prepF[0], pc0 = prepC[0];
    float pf1 = 0.f, pc1 = 0.f;
    if (NT > 1) { pf1 = prepF[TSTRIDE]; pc1 = prepC[TSTRIDE]; }
    int off0 = 2 * TSTRIDE;   // body0 refill: even steps t+2
    int off1 = 3 * TSTRIDE;   // body1 refill: odd steps t+3
    __syncthreads();   // pre-loop: full drain once, harmless

    const f32x4 zz = {0.f, 0.f, 0.f, 0.f};

    // One timestep. MFMAs: 4 independent then 4 dependent (chain depth 2).
    // Step-end barrier = lgkmcnt(0)-only: prefetch VMEM stays in flight.
#define STEP_BODY(CUR, NXT, PF, PC, OFF, TLD)                                   \
    do {                                                                        \
        const short* hb = &h_s[CUR][0];                                         \
        bf16x8 a0 = *(const bf16x8*)(hb + 0*32 + kb);                           \
        bf16x8 a1 = *(const bf16x8*)(hb + 1*32 + kb);                           \
        bf16x8 a2 = *(const bf16x8*)(hb + 2*32 + kb);                           \
        bf16x8 a3 = *(const bf16x8*)(hb + 3*32 + kb);                           \
        float af_in = PF, ac_in = PC;                                           \
        if ((TLD) < NT) { PF = prepF[OFF]; PC = prepC[OFF]; }                   \
        OFF += 2 * TSTRIDE;                                                     \
        f32x4 fa = __builtin_amdgcn_mfma_f32_16x16x32_bf16(a0, bF[0], zz, 0,0,0);\
        f32x4 ga = __builtin_amdgcn_mfma_f32_16x16x32_bf16(a0, bC[0], zz, 0,0,0);\
        f32x4 fb = __builtin_amdgcn_mfma_f32_16x16x32_bf16(a2, bF[2], zz, 0,0,0);\
        f32x4 gb = __builtin_amdgcn_mfma_f32_16x16x32_bf16(a2, bC[2], zz, 0,0,0);\
        fa = __builtin_amdgcn_mfma_f32_16x16x32_bf16(a1, bF[1], fa, 0,0,0);     \
        ga = __builtin_amdgcn_mfma_f32_16x16x32_bf16(a1, bC[1], ga, 0,0,0);     \
        fb = __builtin_amdgcn_mfma_f32_16x16x32_bf16(a3, bF[3], fb, 0,0,0);     \
        gb = __builtin_amdgcn_mfma_f32_16x16x32_bf16(a3, bC[3], gb, 0,0,0);     \
        float af = af_in + (fa[0] + fb[0]);                                     \
        float ac = ac_in + (ga[0] + gb[0]);                                     \
        float gg = sigmoidf_(af);                                               \
        float ct = tanh_fast(ac);                                               \
        c = gg * (c + ct);                                                      \
        float hn = gg * tanh_fast(c);                                           \
        h_last = hn;                                                            \
        if (lane < 16) h_s[NXT][jj] = f2bf_hw(hn);                              \
        lds_only_barrier();                                                     \
    } while (0)

    int t = 0;
    for (; t + 1 < NT; t += 2) {
        STEP_BODY(0, 1, pf0, pc0, off0, t + 2);
        STEP_BODY(1, 0, pf1, pc1, off1, t + 3);
    }
    if (t < NT) { STEP_BODY(0, 1, pf0, pc0, off0, t + 2); }
#undef STEP_BODY

    if (t1 == S) {
        if (lane < 16) red_s[jj] = h_last * Wfc[jj];
        __syncthreads();
        if (tid < 64) {
            float s = red_s[tid] + red_s[tid + 64];
            s += __shfl_down(s, 32, 64);
            s += __shfl_down(s, 16, 64);
            s += __shfl_down(s, 8, 64);
            s += __shfl_down(s, 4, 64);
            s += __shfl_down(s, 2, 64);
            s += __shfl_down(s, 1, 64);
            if (tid == 0) out[b] = sigmoidf_(s + bfc[0]);
        }
    } else {
        if (lane < 16) {
            state[(size_t)b * LSTM_H + jj] = h_last;
            state[LSTM_B * LSTM_H + (size_t)b * LSTM_H + jj] = c;
        }
    }
}

extern "C" void kernel_launch(void* const* d_in, const int* in_sizes, int n_in,
                              void* d_out, int out_size, void* d_ws, size_t ws_size,
                              hipStream_t stream) {
    const int*   x   = (const int*)d_in[0];
    const float* emb = (const float*)d_in[1];
    const float* Wf  = (const float*)d_in[2];
    const float* bf  = (const float*)d_in[3];
    const float* Wc  = (const float*)d_in[4];
    const float* bc  = (const float*)d_in[5];
    const float* Wfc = (const float*)d_in[6];
    const float* bfc = (const float*)d_in[7];
    float* out = (float*)d_out;

    const int S = in_sizes[0] / LSTM_B;           // 2048

    float* state = (float*)d_ws;                              // h[64][128], c[64][128]
    float* pre   = state + (size_t)2 * LSTM_B * LSTM_H;       // + 64KB

    const size_t state_bytes = (size_t)2 * LSTM_B * LSTM_H * sizeof(float);
    const size_t per_t_bytes = (size_t)TSTRIDE * sizeof(float);   // 64 KB per step
    size_t avail = (ws_size > state_bytes) ? (ws_size - state_bytes) : 0;
    int CH = (int)(avail / per_t_bytes);
    if (CH > S) CH = S;
    if (CH < 1) CH = 1;   // requires ws_size >= 128KB + state

    for (int t0 = 0; t0 < S; t0 += CH) {
        const int t1 = (t0 + CH < S) ? (t0 + CH) : S;
        const int nblocksA = ((t1 - t0) * LSTM_B + 127) / 128;
        lstm_phaseA<<<nblocksA, 512, 0, stream>>>(x, emb, Wf, bf, Wc, bc,
                                                  pre, t0, t1, S);
        lstm_phaseB<<<LSTM_B, 512, 0, stream>>>(Wf, Wc, Wfc, bfc, pre, state,
                                                out, t0, t1, S);
    }
}